// Round 4
// baseline (717.318 us; speedup 1.0000x reference)
//
#include <hip/hip_runtime.h>
#include <hip/hip_fp16.h>

#define BATCH   65536
#define IN_DIM  784
#define KPAD    800      // padded K per half (hi or lo)
#define K2      1600     // total GEMM K = [hi | lo]
#define H_DIM   1024
#define C_DIM   10
#define BN_EPS  1e-5f

typedef _Float16 half8 __attribute__((ext_vector_type(8)));
typedef _Float16 half4 __attribute__((ext_vector_type(4)));
typedef float    f32x4 __attribute__((ext_vector_type(4)));

#if defined(__has_builtin)
#if __has_builtin(__builtin_amdgcn_global_load_lds)
#define HAVE_ASYNC 1
#endif
#endif
#ifndef HAVE_ASYNC
#define HAVE_ASYNC 0
#endif

// Stage 16B/lane from global into LDS. Async path: wave-uniform LDS base,
// HW scatters lane i -> base + i*16 (layout contiguous in lane order).
__device__ __forceinline__ void stage16(const _Float16* g, _Float16* ldsBase, int lane) {
#if HAVE_ASYNC
  __builtin_amdgcn_global_load_lds((const __attribute__((address_space(1))) void*)g,
                                   (__attribute__((address_space(3))) void*)ldsBase,
                                   16, 0, 0);
#else
  *(half8*)(ldsBase + lane * 8) = *(const half8*)g;
#endif
}

// ---------------------------------------------------------------------------
// K1: split x (fp32) into fp16 hi/lo halves, K-concatenated:
//     X2[b] = [hi(784) 0pad | lo(784) 0pad]
// ---------------------------------------------------------------------------
__global__ __launch_bounds__(256) void split_x(const float* __restrict__ x,
                                               _Float16* __restrict__ X2) {
  const long tid = (long)blockIdx.x * 256 + threadIdx.x;   // BATCH*200 threads
  const long row = tid / 200;
  const int  q   = (int)(tid - row * 200);
  const int  k   = q * 4;
  half4 hi = {}, lo = {};
  if (k < IN_DIM) {                       // 784 = 4*196, exact
    const f32x4 v = *(const f32x4*)&x[row * IN_DIM + k];
#pragma unroll
    for (int i = 0; i < 4; ++i) {
      const _Float16 h = (_Float16)v[i];
      hi[i] = h;
      lo[i] = (_Float16)(v[i] - (float)h);
    }
  }
  _Float16* dst = X2 + row * K2 + k;
  *(half4*)dst = hi;
  *(half4*)(dst + KPAD) = lo;
}

// ---------------------------------------------------------------------------
// K2: weight prep. Blocks 0..1023: alpha1[j]=mean|w1[j]|, S2[j]=[sign|0pad|sign|0pad] fp16.
//     Blocks 1024..1033: bw2[c][j] = mean|w2[c]| * sign(w2[c][j]) fp32.
// ---------------------------------------------------------------------------
__global__ __launch_bounds__(256) void prep_w(const float* __restrict__ w1,
                                              const float* __restrict__ w2,
                                              float* __restrict__ alpha1,
                                              _Float16* __restrict__ S2,
                                              float* __restrict__ bw2) {
  __shared__ float red[4];
  const int tid = threadIdx.x, lane = tid & 63, wave = tid >> 6;
  const int j = blockIdx.x;
  if (j < H_DIM) {
    const float* wr = w1 + (long)j * IN_DIM;
    float s = 0.f;
    for (int k = tid; k < IN_DIM; k += 256) s += fabsf(wr[k]);
#pragma unroll
    for (int off = 32; off > 0; off >>= 1) s += __shfl_xor(s, off, 64);
    if (lane == 0) red[wave] = s;
    __syncthreads();
    if (tid == 0) alpha1[j] = (red[0] + red[1] + red[2] + red[3]) * (1.f / IN_DIM);
    _Float16* dr = S2 + (long)j * K2;
    for (int k = tid; k < KPAD; k += 256) {
      const float v = (k < IN_DIM) ? wr[k] : 0.f;
      const _Float16 sg = (_Float16)((v > 0.f) ? 1.f : ((v < 0.f) ? -1.f : 0.f));
      dr[k] = sg;
      dr[KPAD + k] = sg;
    }
  } else {
    const int c = j - H_DIM;
    const float* wr = w2 + (long)c * H_DIM;
    float s = 0.f;
    for (int k = tid; k < H_DIM; k += 256) s += fabsf(wr[k]);
#pragma unroll
    for (int off = 32; off > 0; off >>= 1) s += __shfl_xor(s, off, 64);
    if (lane == 0) red[wave] = s;
    __syncthreads();
    const float alpha = (red[0] + red[1] + red[2] + red[3]) * (1.f / H_DIM);
    for (int k = tid; k < H_DIM; k += 256) {
      const float v = wr[k];
      const float sg = (v > 0.f) ? 1.f : ((v < 0.f) ? -1.f : 0.f);
      bw2[(long)c * H_DIM + k] = alpha * sg;
    }
  }
}

// ---------------------------------------------------------------------------
// K3: GEMM1  H[b][j] = alpha1[j] * sum_k X2[b][k]*S2[j][k]   (M=65536,N=1024,K=1600)
// R2: zero-conflict XOR swizzle + fused BN col-stats.
// R3: XCD-aware remap (FETCH 849->185 MB, verified).
// R4: single-barrier double-buffered K-loop. Prefetch for iter k+1 is issued
//     right after the barrier of iter k, then 16 MFMA run before the next
//     barrier's vmcnt(0) drain -> staging latency hidden behind the MFMA
//     phase, and barriers/iter drop 2->1. H stored fp16 (halves H traffic;
//     sign-boundary flip risk ~1e-2, see journal).
// ---------------------------------------------------------------------------
__global__ __launch_bounds__(256) void gemm1(const _Float16* __restrict__ X2,
                                             const _Float16* __restrict__ S2,
                                             const float* __restrict__ alpha1,
                                             _Float16* __restrict__ Hh,
                                             float* __restrict__ colsum,
                                             float* __restrict__ colsumsq) {
  __shared__ _Float16 As[2][128 * 32];
  __shared__ _Float16 Bs[2][128 * 32];
  const int tid  = threadIdx.x;
  const int lane = tid & 63;
  const int wave = tid >> 6;

  // XCD-aware remap: 4096 blocks -> (mt, nt); b%8 = XCD id on MI355X.
  const int b     = blockIdx.x;
  const int xcd   = b & 7;
  const int local = b >> 3;                 // 0..511, sequential within XCD
  const int m0 = (xcd * 64 + (local >> 3)) * 128;
  const int n0 = (local & 7) * 128;

  const int wm = (wave >> 1) * 64;
  const int wn = (wave & 1) * 64;

  // staging: swizzled source chunk per lane (zero-conflict, verified R2)
  const int  kcg  = (lane & 3) ^ ((lane >> 3) & 3);
  const long aRow = (long)(m0 + wave * 32 + (lane >> 2));
  const long bRow = (long)(n0 + wave * 32 + (lane >> 2));
  const _Float16* aG = X2 + aRow * K2 + kcg * 8;
  const _Float16* bG = S2 + bRow * K2 + kcg * 8;
  // wave stages rows [wave*32, wave*32+32): offset wave*32*32 halves, +512 for rows 16..31
  _Float16* aBuf0 = &As[0][wave * 1024];
  _Float16* aBuf1 = &As[1][wave * 1024];
  _Float16* bBuf0 = &Bs[0][wave * 1024];
  _Float16* bBuf1 = &Bs[1][wave * 1024];

  f32x4 acc[4][4] = {};
  const int fr = lane & 15;         // m (A) / n (B) within 16
  const int kc = lane >> 4;         // K 16B-chunk index
  const int frag = (fr * 4 + (kc ^ ((fr >> 1) & 3))) * 8;
  const int abase = (wm >> 4) * 512 + frag;   // window = 16 rows * 32 halves = 512
  const int bbase = (wn >> 4) * 512 + frag;

  // prologue: stage first tile into buffer 0 (no readers yet, no barrier needed)
  stage16(aG, aBuf0, lane);
  stage16(aG + 16 * K2, aBuf0 + 512, lane);
  stage16(bG, bBuf0, lane);
  stage16(bG + 16 * K2, bBuf0 + 512, lane);

  for (int ks = 0; ks < K2 / 32; ++ks) {
    const int cur = ks & 1;
    __syncthreads();   // drains prefetch of buf[cur]; all prior reads of buf[cur^1] done
    if (ks < K2 / 32 - 1) {
      const int kn = (ks + 1) * 32;
      _Float16* aD = cur ? aBuf0 : aBuf1;
      _Float16* bD = cur ? bBuf0 : bBuf1;
      stage16(aG + kn, aD, lane);
      stage16(aG + 16 * K2 + kn, aD + 512, lane);
      stage16(bG + kn, bD, lane);
      stage16(bG + 16 * K2 + kn, bD + 512, lane);
    }
    const _Float16* Ab = &As[cur][0];
    const _Float16* Bb = &Bs[cur][0];
    half8 af[4], bf[4];
#pragma unroll
    for (int i = 0; i < 4; ++i) af[i] = *(const half8*)&Ab[abase + i * 512];
#pragma unroll
    for (int i = 0; i < 4; ++i) bf[i] = *(const half8*)&Bb[bbase + i * 512];
#pragma unroll
    for (int mi = 0; mi < 4; ++mi)
#pragma unroll
      for (int ni = 0; ni < 4; ++ni)
        acc[mi][ni] = __builtin_amdgcn_mfma_f32_16x16x32_f16(af[mi], bf[ni], acc[mi][ni], 0, 0, 0);
  }

  // epilogue: D layout col=lane&15, row=(lane>>4)*4+r  [measured m89/m91]
  // + fused column sum/sumsq; H stored fp16
  const int rq = (lane >> 4) * 4;
#pragma unroll
  for (int ni = 0; ni < 4; ++ni) {
    const int col = n0 + wn + ni * 16 + fr;
    const float a1 = alpha1[col];
    float s = 0.f, q = 0.f;
#pragma unroll
    for (int mi = 0; mi < 4; ++mi) {
#pragma unroll
      for (int r = 0; r < 4; ++r) {
        const int row = m0 + wm + mi * 16 + rq + r;
        const float v = acc[mi][ni][r] * a1;
        Hh[(long)row * H_DIM + col] = (_Float16)v;
        s += v;
        q += v * v;
      }
    }
    s += __shfl_xor(s, 16, 64);
    s += __shfl_xor(s, 32, 64);
    q += __shfl_xor(q, 16, 64);
    q += __shfl_xor(q, 32, 64);
    if ((lane >> 4) == 0) {
      atomicAdd(&colsum[col], s);
      atomicAdd(&colsumsq[col], q);
    }
  }
}

// ---------------------------------------------------------------------------
// K5: normalize -> sign -> out = a @ bw2^T. One wave per batch row. H is fp16.
// ---------------------------------------------------------------------------
__global__ __launch_bounds__(256) void final_k(const _Float16* __restrict__ Hh,
                                               const float* __restrict__ colsum,
                                               const float* __restrict__ colsumsq,
                                               const float* __restrict__ gamma,
                                               const float* __restrict__ beta,
                                               const float* __restrict__ bw2,
                                               float* __restrict__ out) {
  __shared__ float cs[H_DIM], ts[H_DIM];
  __shared__ float w2s[C_DIM * H_DIM];   // [oc][j] layout -> b128, conflict-free
  const int tid = threadIdx.x, lane = tid & 63, wave = tid >> 6;
  for (int j = tid; j < H_DIM; j += 256) {
    const float mu  = colsum[j] * (1.f / BATCH);
    const float var = colsumsq[j] * (1.f / BATCH) - mu * mu;  // biased var
    const float c   = gamma[j] * rsqrtf(var + BN_EPS);
    cs[j] = c;
    ts[j] = beta[j] - c * mu;             // sign(gamma*(h-mu)*invstd+beta) = sign(c*h+t)
  }
  for (int i = tid; i < C_DIM * H_DIM; i += 256) w2s[i] = bw2[i];
  __syncthreads();

  for (long row = (long)blockIdx.x * 4 + wave; row < BATCH; row += (long)gridDim.x * 4) {
    float p[C_DIM] = {};
#pragma unroll
    for (int c8 = 0; c8 < 2; ++c8) {
      const int col = c8 * 512 + lane * 8;
      const half8 hv = *(const half8*)&Hh[row * H_DIM + col];
      float a[8];
#pragma unroll
      for (int i = 0; i < 8; ++i) {
        const float hvf = (float)hv[i] * cs[col + i] + ts[col + i];
        a[i] = (hvf > 0.f) ? 1.f : ((hvf < 0.f) ? -1.f : 0.f);   // jnp.sign semantics
      }
#pragma unroll
      for (int oc = 0; oc < C_DIM; ++oc) {
        const f32x4 w0 = *(const f32x4*)&w2s[oc * H_DIM + col];
        const f32x4 w1v = *(const f32x4*)&w2s[oc * H_DIM + col + 4];
        p[oc] += a[0] * w0[0] + a[1] * w0[1] + a[2] * w0[2] + a[3] * w0[3]
               + a[4] * w1v[0] + a[5] * w1v[1] + a[6] * w1v[2] + a[7] * w1v[3];
      }
    }
#pragma unroll
    for (int oc = 0; oc < C_DIM; ++oc)
#pragma unroll
      for (int off = 32; off > 0; off >>= 1)
        p[oc] += __shfl_xor(p[oc], off, 64);
    if (lane == 0) {
#pragma unroll
      for (int oc = 0; oc < C_DIM; ++oc) out[row * C_DIM + oc] = p[oc];
    }
  }
}

// ---------------------------------------------------------------------------
extern "C" void kernel_launch(void* const* d_in, const int* in_sizes, int n_in,
                              void* d_out, int out_size, void* d_ws, size_t ws_size,
                              hipStream_t stream) {
  const float* x     = (const float*)d_in[0];
  const float* w1    = (const float*)d_in[1];
  const float* w2    = (const float*)d_in[2];
  const float* gamma = (const float*)d_in[3];
  const float* beta  = (const float*)d_in[4];
  float* out = (float*)d_out;

  // workspace layout (bytes); offsets kept from R1-R3 (proven within ws_size)
  char* ws = (char*)d_ws;
  _Float16* X2     = (_Float16*)(ws + 0);            // 65536*1600*2 = 209,715,200
  _Float16* Hh     = (_Float16*)(ws + 209715200LL);  // 65536*1024*2 = 134,217,728 (fp16 now)
  _Float16* S2     = (_Float16*)(ws + 478150656LL);  // 1024*1600*2  =   3,276,800
  float*    BW2    = (float*)  (ws + 481427456LL);   // 10*1024*4    =      40,960
  float*    ALPHA1 = (float*)  (ws + 481468416LL);   // 1024*4       =       4,096
  float*    COLS   = (float*)  (ws + 481472512LL);   // 1024*4
  float*    COLQ   = (float*)  (ws + 481476608LL);   // 1024*4 (contiguous w/ COLS)

  hipMemsetAsync(COLS, 0, 2 * H_DIM * sizeof(float), stream);  // ws is poisoned each call
  split_x<<<(BATCH * 200) / 256, 256, 0, stream>>>(x, X2);
  prep_w<<<H_DIM + C_DIM, 256, 0, stream>>>(w1, w2, ALPHA1, S2, BW2);
  gemm1<<<4096, 256, 0, stream>>>(X2, S2, ALPHA1, Hh, COLS, COLQ);
  final_k<<<2048, 256, 0, stream>>>(Hh, COLS, COLQ, gamma, beta, BW2, out);
}

// Round 5
// 714.486 us; speedup vs baseline: 1.0040x; 1.0040x over previous
//
#include <hip/hip_runtime.h>
#include <hip/hip_fp16.h>

#define BATCH   65536
#define IN_DIM  784
#define K2      1600     // GEMM K: 200 chunks of [hi4|lo4]
#define H_DIM   1024
#define C_DIM   10
#define CPAD    16       // padded output cols for MFMA
#define BROW    1032     // BW2h row stride in halves (+8 pad: bank spread, 16B-aligned)
#define BN_EPS  1e-5f

typedef _Float16 half8 __attribute__((ext_vector_type(8)));
typedef float    f32x4 __attribute__((ext_vector_type(4)));

#if defined(__has_builtin)
#if __has_builtin(__builtin_amdgcn_global_load_lds)
#define HAVE_ASYNC 1
#endif
#endif
#ifndef HAVE_ASYNC
#define HAVE_ASYNC 0
#endif

__device__ __forceinline__ void stage16(const _Float16* g, _Float16* ldsBase, int lane) {
#if HAVE_ASYNC
  __builtin_amdgcn_global_load_lds((const __attribute__((address_space(1))) void*)g,
                                   (__attribute__((address_space(3))) void*)ldsBase,
                                   16, 0, 0);
#else
  *(half8*)(ldsBase + lane * 8) = *(const half8*)g;
#endif
}

__device__ __forceinline__ float signf(float v) {
  return (v > 0.f) ? 1.f : ((v < 0.f) ? -1.f : 0.f);   // jnp.sign semantics
}

// ---------------------------------------------------------------------------
// K1: split x into fp16 hi/lo, interleaved per 4-elem chunk:
//     X2[row][8q..8q+7] = [hi(x[4q..4q+3]) | lo(x[4q..4q+3])] -> one 16B store.
//     Chunks q>=196 are zero (784=4*196; K2=1600=8*200).
// ---------------------------------------------------------------------------
__global__ __launch_bounds__(256) void split_x(const float* __restrict__ x,
                                               _Float16* __restrict__ X2) {
  const unsigned tid = blockIdx.x * 256 + threadIdx.x;   // BATCH*200 threads
  const unsigned row = tid / 200u;                       // 32-bit magic-mul div
  const int      q   = (int)(tid - row * 200u);
  half8 o = {};
  if (q < 196) {
    const f32x4 v = *(const f32x4*)&x[(long)row * IN_DIM + q * 4];
#pragma unroll
    for (int i = 0; i < 4; ++i) {
      const _Float16 h = (_Float16)v[i];
      o[i]     = h;
      o[i + 4] = (_Float16)(v[i] - (float)h);
    }
  }
  *(half8*)&X2[(long)row * K2 + q * 8] = o;
}

// ---------------------------------------------------------------------------
// K2: weight prep.
//  Blocks 0..1023: alpha1[j]=mean|w1[j]|; S2[j] sign pattern matching split_x
//     interleave: chunk q -> [s0..s3 | s0..s3].
//  Blocks 1024..1039: BW2h[c][k] = (fp16) mean|w2[c]| * sign(w2[c][k]),
//     rows 10..15 and pad cols [1024,1032) zeroed.
// ---------------------------------------------------------------------------
__global__ __launch_bounds__(256) void prep_w(const float* __restrict__ w1,
                                              const float* __restrict__ w2,
                                              float* __restrict__ alpha1,
                                              _Float16* __restrict__ S2,
                                              _Float16* __restrict__ BW2h) {
  __shared__ float red[4];
  const int tid = threadIdx.x, lane = tid & 63, wave = tid >> 6;
  const int j = blockIdx.x;
  if (j < H_DIM) {
    const float* wr = w1 + (long)j * IN_DIM;
    float s = 0.f;
    for (int k = tid; k < IN_DIM; k += 256) s += fabsf(wr[k]);
#pragma unroll
    for (int off = 32; off > 0; off >>= 1) s += __shfl_xor(s, off, 64);
    if (lane == 0) red[wave] = s;
    __syncthreads();
    if (tid == 0) alpha1[j] = (red[0] + red[1] + red[2] + red[3]) * (1.f / IN_DIM);
    _Float16* dr = S2 + (long)j * K2;
    for (int q = tid; q < 200; q += 256) {
      half8 o;
#pragma unroll
      for (int i = 0; i < 4; ++i) {
        const int k = q * 4 + i;
        const _Float16 sg = (_Float16)((k < IN_DIM) ? signf(wr[k]) : 0.f);
        o[i]     = sg;
        o[i + 4] = sg;
      }
      *(half8*)&dr[q * 8] = o;
    }
  } else {
    const int c = j - H_DIM;                  // 0..15
    float alpha = 0.f;
    if (c < C_DIM) {
      const float* wr = w2 + (long)c * H_DIM;
      float s = 0.f;
      for (int k = tid; k < H_DIM; k += 256) s += fabsf(wr[k]);
#pragma unroll
      for (int off = 32; off > 0; off >>= 1) s += __shfl_xor(s, off, 64);
      if (lane == 0) red[wave] = s;
      __syncthreads();
      alpha = (red[0] + red[1] + red[2] + red[3]) * (1.f / H_DIM);
    }
    for (int k = tid; k < BROW; k += 256) {
      float v = 0.f;
      if (c < C_DIM && k < H_DIM) v = alpha * signf(w2[(long)c * H_DIM + k]);
      BW2h[(long)c * BROW + k] = (_Float16)v;
    }
  }
}

// ---------------------------------------------------------------------------
// K3: GEMM1  H[b][j] = alpha1[j] * sum_k X2[b][k]*S2[j][k]   (M=65536,N=1024,K=1600)
// R2: zero-conflict XOR swizzle + fused BN col-stats (verified: conflicts=0).
// R3: XCD-aware remap (verified: FETCH 849->185 MB).
// R4 dbuf REVERTED (regressed 336->360; m99/m100-consistent). fp16 H kept.
// ---------------------------------------------------------------------------
__global__ __launch_bounds__(256) void gemm1(const _Float16* __restrict__ X2,
                                             const _Float16* __restrict__ S2,
                                             const float* __restrict__ alpha1,
                                             _Float16* __restrict__ Hh,
                                             float* __restrict__ colsum,
                                             float* __restrict__ colsumsq) {
  __shared__ _Float16 As[128 * 32];
  __shared__ _Float16 Bs[128 * 32];
  const int tid  = threadIdx.x;
  const int lane = tid & 63;
  const int wave = tid >> 6;

  // XCD-aware remap: b%8 = XCD id on MI355X.
  const int b     = blockIdx.x;
  const int xcd   = b & 7;
  const int local = b >> 3;                 // 0..511
  const int m0 = (xcd * 64 + (local >> 3)) * 128;
  const int n0 = (local & 7) * 128;

  const int wm = (wave >> 1) * 64;
  const int wn = (wave & 1) * 64;

  // staging: swizzled source chunk per lane (zero-conflict, verified R2)
  const int  kcg  = (lane & 3) ^ ((lane >> 3) & 3);
  const long aRow = (long)(m0 + wave * 32 + (lane >> 2));
  const long bRow = (long)(n0 + wave * 32 + (lane >> 2));
  const _Float16* aG = X2 + aRow * K2 + kcg * 8;
  const _Float16* bG = S2 + bRow * K2 + kcg * 8;
  _Float16* aL  = &As[(wave * 32) * 32];
  _Float16* aL2 = &As[(wave * 32 + 16) * 32];
  _Float16* bL  = &Bs[(wave * 32) * 32];
  _Float16* bL2 = &Bs[(wave * 32 + 16) * 32];

  f32x4 acc[4][4] = {};
  const int fr = lane & 15;
  const int kc = lane >> 4;
  const int frag = (fr * 4 + (kc ^ ((fr >> 1) & 3))) * 8;
  const int abase = (wm >> 4) * 512 + frag;
  const int bbase = (wn >> 4) * 512 + frag;

  for (int ks = 0; ks < K2 / 32; ++ks) {
    const int k0 = ks * 32;
    __syncthreads();
    stage16(aG + k0, aL, lane);
    stage16(aG + 16 * K2 + k0, aL2, lane);
    stage16(bG + k0, bL, lane);
    stage16(bG + 16 * K2 + k0, bL2, lane);
    __syncthreads();
    half8 af[4], bf[4];
#pragma unroll
    for (int i = 0; i < 4; ++i) af[i] = *(const half8*)&As[abase + i * 512];
#pragma unroll
    for (int i = 0; i < 4; ++i) bf[i] = *(const half8*)&Bs[bbase + i * 512];
#pragma unroll
    for (int mi = 0; mi < 4; ++mi)
#pragma unroll
      for (int ni = 0; ni < 4; ++ni)
        acc[mi][ni] = __builtin_amdgcn_mfma_f32_16x16x32_f16(af[mi], bf[ni], acc[mi][ni], 0, 0, 0);
  }

  // epilogue: D layout col=lane&15, row=(lane>>4)*4+r + fused col stats; H fp16
  const int rq = (lane >> 4) * 4;
#pragma unroll
  for (int ni = 0; ni < 4; ++ni) {
    const int col = n0 + wn + ni * 16 + fr;
    const float a1 = alpha1[col];
    float s = 0.f, q = 0.f;
#pragma unroll
    for (int mi = 0; mi < 4; ++mi) {
#pragma unroll
      for (int r = 0; r < 4; ++r) {
        const int row = m0 + wm + mi * 16 + rq + r;
        const float v = acc[mi][ni][r] * a1;
        Hh[(long)row * H_DIM + col] = (_Float16)v;
        s += v;
        q += v * v;
      }
    }
    s += __shfl_xor(s, 16, 64);
    s += __shfl_xor(s, 32, 64);
    q += __shfl_xor(q, 16, 64);
    q += __shfl_xor(q, 32, 64);
    if ((lane >> 4) == 0) {
      atomicAdd(&colsum[col], s);
      atomicAdd(&colsumsq[col], q);
    }
  }
}

// ---------------------------------------------------------------------------
// K4: gemm2 — out[b][c] = sum_j sign(cs[j]*H[b][j]+ts[j]) * BW2h[c][j] via MFMA.
// Block: 256 thr = 4 waves x 32 rows = 128 rows. B (16x1024 fp16) staged once
// in LDS; A-frags read DIRECT from global H in MFMA A-layout
// (A[m=lane&15][k=(lane>>4)*8+j], m120-verified), sign applied in-register.
// No shuffles, no atomics, no per-row reductions (R4 finding: old final_k was
// DS-pipe-bound at ~105 us: 20 b128 + 60 shfl per row).
// ---------------------------------------------------------------------------
__global__ __launch_bounds__(256) void gemm2(const _Float16* __restrict__ Hh,
                                             const float* __restrict__ colsum,
                                             const float* __restrict__ colsumsq,
                                             const float* __restrict__ gamma,
                                             const float* __restrict__ beta,
                                             const _Float16* __restrict__ BW2h,
                                             float* __restrict__ out) {
  __shared__ float cs[H_DIM], ts[H_DIM];
  __shared__ _Float16 Bsh[CPAD * BROW];
  const int tid = threadIdx.x, lane = tid & 63, wave = tid >> 6;
  for (int j = tid; j < H_DIM; j += 256) {
    const float mu  = colsum[j] * (1.f / BATCH);
    const float var = colsumsq[j] * (1.f / BATCH) - mu * mu;
    const float c   = gamma[j] * rsqrtf(var + BN_EPS);
    cs[j] = c;
    ts[j] = beta[j] - c * mu;
  }
  for (int i = tid; i < CPAD * BROW / 8; i += 256)
    *(half8*)&Bsh[i * 8] = *(const half8*)&BW2h[i * 8];
  __syncthreads();

  // XCD-matched row mapping (H written XCD-major by gemm1)
  const int b    = blockIdx.x;                       // 512 blocks
  const int row0 = (b & 7) * 8192 + (b >> 3) * 128;
  const int wrow = row0 + wave * 32;                 // wave: rows [wrow, wrow+32)
  const int fr = lane & 15;
  const int kq = (lane >> 4) * 8;

  f32x4 acc0 = {}, acc1 = {};
  const _Float16* h0p = Hh + (long)(wrow + fr) * H_DIM + kq;
  const _Float16* h1p = Hh + (long)(wrow + 16 + fr) * H_DIM + kq;
  const _Float16* bfp = &Bsh[fr * BROW + kq];

  for (int it = 0; it < H_DIM / 32; ++it) {
    const int k0 = it * 32;
    const half8 bf = *(const half8*)(bfp + k0);
    const half8 h0 = *(const half8*)(h0p + k0);
    const half8 h1 = *(const half8*)(h1p + k0);
    const f32x4 c0 = *(const f32x4*)&cs[k0 + kq];
    const f32x4 c1 = *(const f32x4*)&cs[k0 + kq + 4];
    const f32x4 t0 = *(const f32x4*)&ts[k0 + kq];
    const f32x4 t1 = *(const f32x4*)&ts[k0 + kq + 4];
    half8 a0, a1;
#pragma unroll
    for (int i = 0; i < 4; ++i) {
      a0[i]     = (_Float16)signf((float)h0[i] * c0[i] + t0[i]);
      a0[i + 4] = (_Float16)signf((float)h0[i + 4] * c1[i] + t1[i]);
      a1[i]     = (_Float16)signf((float)h1[i] * c0[i] + t0[i]);
      a1[i + 4] = (_Float16)signf((float)h1[i + 4] * c1[i] + t1[i]);
    }
    acc0 = __builtin_amdgcn_mfma_f32_16x16x32_f16(a0, bf, acc0, 0, 0, 0);
    acc1 = __builtin_amdgcn_mfma_f32_16x16x32_f16(a1, bf, acc1, 0, 0, 0);
  }

  // D layout: col=lane&15 (=oc), row=(lane>>4)*4+r
  if (fr < C_DIM) {
    const int rb = (lane >> 4) * 4;
#pragma unroll
    for (int r = 0; r < 4; ++r) {
      out[(long)(wrow + rb + r) * C_DIM + fr]      = acc0[r];
      out[(long)(wrow + 16 + rb + r) * C_DIM + fr] = acc1[r];
    }
  }
}

// ---------------------------------------------------------------------------
extern "C" void kernel_launch(void* const* d_in, const int* in_sizes, int n_in,
                              void* d_out, int out_size, void* d_ws, size_t ws_size,
                              hipStream_t stream) {
  const float* x     = (const float*)d_in[0];
  const float* w1    = (const float*)d_in[1];
  const float* w2    = (const float*)d_in[2];
  const float* gamma = (const float*)d_in[3];
  const float* beta  = (const float*)d_in[4];
  float* out = (float*)d_out;

  char* ws = (char*)d_ws;
  _Float16* X2     = (_Float16*)(ws + 0);            // 65536*1600*2 = 209,715,200
  _Float16* Hh     = (_Float16*)(ws + 209715200LL);  // 65536*1024*2 = 134,217,728
  _Float16* S2     = (_Float16*)(ws + 478150656LL);  // 1024*1600*2  =   3,276,800
  _Float16* BW2h   = (_Float16*)(ws + 481427456LL);  // 16*1032*2    =      33,024
  float*    ALPHA1 = (float*)  (ws + 481468416LL);   // 1024*4
  float*    COLS   = (float*)  (ws + 481472512LL);   // 1024*4
  float*    COLQ   = (float*)  (ws + 481476608LL);   // 1024*4

  hipMemsetAsync(COLS, 0, 2 * H_DIM * sizeof(float), stream);
  split_x<<<(BATCH * 200) / 256, 256, 0, stream>>>(x, X2);
  prep_w<<<H_DIM + CPAD, 256, 0, stream>>>(w1, w2, ALPHA1, S2, BW2h);
  gemm1<<<4096, 256, 0, stream>>>(X2, S2, ALPHA1, Hh, COLS, COLQ);
  gemm2<<<512, 256, 0, stream>>>(Hh, COLS, COLQ, gamma, beta, BW2h, out);
}